// Round 4
// baseline (141.869 us; speedup 1.0000x reference)
//
#include <hip/hip_runtime.h>
#include <math.h>

#define N_CELLS 65536

// ---- workspace layout (float offsets); ws is ~256 MiB ----
#define OFF_W1B   0          // bf16 [32 sk][256 n][8 j] = 65536 u16 = 32768 f
#define OFF_W2A   32768      // bf16 [32 sk][128 o][8 j] = 32768 u16 = 16384 f
#define OFF_XW1B  49152      // f32 [256]
#define OFF_B2D   49408      // f32 [128]
#define OFF_PT    49536      // f32 [1024]
#define OFF_PE    50560      // f32 [1024]
#define OFF_POUT  51584      // f32 [128 o][1024 blk]  (TRANSPOSED)
#define OFF_MI4   182656     // f32 [32 j4][64 g][4]  mem_in quads
#define OFF_TEN   190848     // f32 [64]
#define OFF_HH4   190912     // f32 [64 j4][64 g][4]
#define OFF_GI    207296     // f32 [768][64]
#define OFF_GH    256448     // f32 [768][64]
#define OFF_PLIM  305600     // f32 [32][256]
#define OFF_PCOL  313792     // f32 [32][256]
#define OFF_H1F   4194304    // u16 h1[65536][256] = 33.55 MB (starts at 16 MB)

typedef short bf16x8 __attribute__((ext_vector_type(8)));
typedef short s16x4  __attribute__((ext_vector_type(4)));
typedef float f32x4  __attribute__((ext_vector_type(4)));

__device__ __forceinline__ unsigned short f2bf(float f) {
    unsigned u = __builtin_bit_cast(unsigned, f);
    u += 0x7FFFu + ((u >> 16) & 1u);          // round-to-nearest-even
    return (unsigned short)(u >> 16);
}

__device__ __forceinline__ bf16x8 cvt8(float4 a, float4 b) {
    bf16x8 v;
    v[0] = (short)f2bf(a.x); v[1] = (short)f2bf(a.y);
    v[2] = (short)f2bf(a.z); v[3] = (short)f2bf(a.w);
    v[4] = (short)f2bf(b.x); v[5] = (short)f2bf(b.y);
    v[6] = (short)f2bf(b.z); v[7] = (short)f2bf(b.w);
    return v;
}

// ---------------------------------------------------------------------------
// Prep: pack W1/W2' to bf16 fragment layout, fold x@W1^T+b1, b2d, and build
// hiddens quads for gathered cells (parallel, 1 block per g). Grid 321 x 256.
// ---------------------------------------------------------------------------
__global__ __launch_bounds__(256) void k_prep(
    const float* __restrict__ x, const float* __restrict__ hiddens,
    const float* __restrict__ Wa1, const float* __restrict__ ba1,
    const float* __restrict__ Wa2, const float* __restrict__ ba2,
    const float* __restrict__ Wg1, const float* __restrict__ bg1,
    const float* __restrict__ Wg2, const float* __restrict__ bg2,
    const int* __restrict__ msrc, const int* __restrict__ mtgt,
    float* __restrict__ ws)
{
    const int b = blockIdx.x, t = threadIdx.x;
    unsigned short* w1b = (unsigned short*)(ws + OFF_W1B);
    unsigned short* w2a = (unsigned short*)(ws + OFF_W2A);
    if (b < 256) {
        const int n = b;           // t = k index (sk = t>>3, j = t&7)
        const float* row = (n < 128) ? &Wa1[n * 384] : &Wg1[(n - 128) * 384];
        const int sk = t >> 3;
        w1b[(sk * 256 + n) * 8 + (t & 7)] = f2bf(row[128 + t]);
        if (n < 128) {   // W2'[o=n][k=t] : k<128 -> Wa2, else -Wg2
            float w2 = (t < 128) ? Wa2[n * 128 + t] : -Wg2[n * 128 + (t - 128)];
            w2a[(sk * 128 + n) * 8 + (t & 7)] = f2bf(w2);
        }
    } else if (b == 256) {
        const int n = t;
        const float* wr = (n < 128) ? &Wa1[n * 384] : &Wg1[(n - 128) * 384];
        float s = (n < 128) ? ba1[n] : bg1[n - 128];
        for (int j = 0; j < 128; ++j) s = fmaf(x[j], wr[j], s);
        ws[OFF_XW1B + n] = s;
        if (n < 128) ws[OFF_B2D + n] = ba2[n] - bg2[n];
    } else {
        const int g = b - 257;     // 0..63
        const int cell = (g < 32) ? msrc[g] : mtgt[g - 32];
        ws[OFF_HH4 + (t >> 2) * 256 + g * 4 + (t & 3)] = hiddens[(size_t)cell * 256 + t];
    }
}

// ---------------------------------------------------------------------------
// GEMM1: h1 = relu(hiddens@W1^T + xw1b), bf16 out.  Grid 256 x 1024.
// W1 resident in LDS (staged once); B-fragments straight from global with
// depth-2 rolling prefetch; no barriers in the main loop.
// 16 waves: wn = wid&3 (64 n), wc = wid>>2 (16 cells). 4 tiles of 64 cells.
// ---------------------------------------------------------------------------
__global__ __launch_bounds__(1024, 4) void k_g1(
    const float* __restrict__ hiddens, float* __restrict__ ws)
{
    __shared__ __align__(16) short w1[65536];   // 128 KB
    const int tid = threadIdx.x;
    {
        const uint4* src = (const uint4*)(ws + OFF_W1B);
        uint4* dst = (uint4*)w1;
#pragma unroll
        for (int i = 0; i < 8; ++i) dst[i * 1024 + tid] = src[i * 1024 + tid];
    }
    __syncthreads();

    const int lane = tid & 63, wid = tid >> 6;
    const int wn = wid & 3, wc = wid >> 2;
    const int l15 = lane & 15, l4 = lane >> 4;

    float4 xb[4];
#pragma unroll
    for (int nt = 0; nt < 4; ++nt)
        xb[nt] = *(const float4*)(ws + OFF_XW1B + wn * 64 + nt * 16 + l4 * 4);

    unsigned short* h1 = (unsigned short*)(ws + OFF_H1F);
    // lane's hiddens row for tile 0 (tiles advance by 64 cells = 16384 floats)
    const float* hbase = hiddens + (size_t)(blockIdx.x * 256 + wc * 16 + l15) * 256;

    // rolling prefetch over global step index g = t*8 + s  (k0 = (g&7)*32 + l4*8)
    float4 A0, B0, A1, B1;
    { const float* p = hbase + l4 * 8;                 A0 = *(const float4*)p; B0 = *(const float4*)(p + 4); }
    { const float* p = hbase + 32 + l4 * 8;            A1 = *(const float4*)p; B1 = *(const float4*)(p + 4); }

    for (int t = 0; t < 4; ++t) {
        f32x4 acc[4];
#pragma unroll
        for (int nt = 0; nt < 4; ++nt) acc[nt] = (f32x4)0.f;

#pragma unroll
        for (int s = 0; s < 8; ++s) {
            bf16x8 bfr = cvt8(A0, B0);
            A0 = A1; B0 = B1;
            const int g = t * 8 + s + 2;
            if (g < 32) {
                const float* p = hbase + (g >> 3) * 16384 + (g & 7) * 32 + l4 * 8;
                A1 = *(const float4*)p; B1 = *(const float4*)(p + 4);
            }
#pragma unroll
            for (int nt = 0; nt < 4; ++nt) {
                bf16x8 afr = *(const bf16x8*)&w1[((s * 4 + l4) * 256 + wn * 64 + nt * 16 + l15) * 8];
                acc[nt] = __builtin_amdgcn_mfma_f32_16x16x32_bf16(afr, bfr, acc[nt], 0, 0, 0);
            }
        }
        // epilogue: bias + relu -> bf16 -> h1[c][n0..n0+3]
        unsigned short* hrow = h1 + (size_t)(blockIdx.x * 256 + t * 64 + wc * 16 + l15) * 256;
#pragma unroll
        for (int nt = 0; nt < 4; ++nt) {
            s16x4 pk;
            pk[0] = (short)f2bf(fmaxf(acc[nt][0] + xb[nt].x, 0.f));
            pk[1] = (short)f2bf(fmaxf(acc[nt][1] + xb[nt].y, 0.f));
            pk[2] = (short)f2bf(fmaxf(acc[nt][2] + xb[nt].z, 0.f));
            pk[3] = (short)f2bf(fmaxf(acc[nt][3] + xb[nt].w, 0.f));
            *(s16x4*)&hrow[wn * 64 + nt * 16 + l4 * 4] = pk;
        }
    }
}

// ---------------------------------------------------------------------------
// GEMM2 + epilogue.  Grid 1024 x 512.  W2' entirely in registers (16 uint4
// A-fragments per lane); B = h1 16B contiguous reads; no staging barriers.
// 8 waves: wn = wid>>1 (32 o), wc = wid&1 (32 cells, 2 ct).
// ---------------------------------------------------------------------------
__global__ __launch_bounds__(512, 4) void k_g2(
    const int* __restrict__ msrc, const int* __restrict__ mtgt,
    float* __restrict__ ws)
{
    __shared__ float out_sm[64 * 130];
    __shared__ float part[256];
    __shared__ float e_sm[64];
    __shared__ float t_sm[64];

    const int tid = threadIdx.x;
    const int lane = tid & 63, wid = tid >> 6;
    const int wn = wid >> 1, wc = wid & 1;
    const int l15 = lane & 15, l4 = lane >> 4;
    const int blk = blockIdx.x;

    // A-fragments: W2' for this wave's 32-o range, all 256 n
    const uint4* w2g = (const uint4*)(ws + OFF_W2A);
    uint4 a2[8][2];
#pragma unroll
    for (int s = 0; s < 8; ++s)
#pragma unroll
        for (int ot = 0; ot < 2; ++ot)
            a2[s][ot] = w2g[(s * 4 + l4) * 128 + wn * 32 + ot * 16 + l15];

    const unsigned short* h1 = (const unsigned short*)(ws + OFF_H1F);
    const unsigned short* hr[2];
#pragma unroll
    for (int ct = 0; ct < 2; ++ct)
        hr[ct] = h1 + (size_t)(blk * 64 + wc * 32 + ct * 16 + l15) * 256;

    f32x4 acc2[2][2];
#pragma unroll
    for (int ot = 0; ot < 2; ++ot)
#pragma unroll
        for (int ct = 0; ct < 2; ++ct) acc2[ot][ct] = (f32x4)0.f;

    uint4 pb0 = *(const uint4*)&hr[0][l4 * 8];
    uint4 pb1 = *(const uint4*)&hr[1][l4 * 8];
#pragma unroll
    for (int s = 0; s < 8; ++s) {
        bf16x8 bfr0 = __builtin_bit_cast(bf16x8, pb0);
        bf16x8 bfr1 = __builtin_bit_cast(bf16x8, pb1);
        if (s < 7) {
            pb0 = *(const uint4*)&hr[0][(s + 1) * 32 + l4 * 8];
            pb1 = *(const uint4*)&hr[1][(s + 1) * 32 + l4 * 8];
        }
#pragma unroll
        for (int ot = 0; ot < 2; ++ot) {
            bf16x8 af = __builtin_bit_cast(bf16x8, a2[s][ot]);
            acc2[ot][0] = __builtin_amdgcn_mfma_f32_16x16x32_bf16(af, bfr0, acc2[ot][0], 0, 0, 0);
            acc2[ot][1] = __builtin_amdgcn_mfma_f32_16x16x32_bf16(af, bfr1, acc2[ot][1], 0, 0, 0);
        }
    }

    // ---- epilogue ----
    float outv[2][2][4];
#pragma unroll
    for (int ot = 0; ot < 2; ++ot) {
        float4 bd = *(const float4*)(ws + OFF_B2D + wn * 32 + ot * 16 + l4 * 4);
        const float bv[4] = {bd.x, bd.y, bd.z, bd.w};
#pragma unroll
        for (int ct = 0; ct < 2; ++ct)
#pragma unroll
            for (int r = 0; r < 4; ++r)
                outv[ot][ct][r] = acc2[ot][ct][r] + bv[r];
    }

#pragma unroll
    for (int ot = 0; ot < 2; ++ot)
#pragma unroll
        for (int ct = 0; ct < 2; ++ct) {
            const int c = wc * 32 + ct * 16 + l15;
#pragma unroll
            for (int r = 0; r < 4; ++r)
                out_sm[c * 130 + wn * 32 + ot * 16 + l4 * 4 + r] = outv[ot][ct][r];
        }
#pragma unroll
    for (int ct = 0; ct < 2; ++ct) {
        float sq = 0.f;
#pragma unroll
        for (int ot = 0; ot < 2; ++ot)
#pragma unroll
            for (int r = 0; r < 4; ++r) sq = fmaf(outv[ot][ct][r], outv[ot][ct][r], sq);
        sq += __shfl_xor(sq, 16);
        sq += __shfl_xor(sq, 32);
        if (l4 == 0) part[wn * 64 + wc * 32 + ct * 16 + l15] = sq;
    }
    __syncthreads();

    if (tid < 64) {
        const float tv = (part[tid] + part[64 + tid] + part[128 + tid] + part[192 + tid]) * (1.f / 128.f);
        const float ev = expf(tv);
        t_sm[tid] = tv; e_sm[tid] = ev;
        float pt = tv, pe = ev;
        for (int off = 32; off > 0; off >>= 1) {
            pt += __shfl_down(pt, off);
            pe += __shfl_down(pe, off);
        }
        if (tid == 0) { ws[OFF_PT + blk] = pt; ws[OFF_PE + blk] = pe; }
    }
    __syncthreads();

    if (tid < 128) {
        float s = 0.f;
        for (int c = 0; c < 64; ++c) s = fmaf(e_sm[c], out_sm[c * 130 + tid], s);
        ws[OFF_POUT + tid * 1024 + blk] = s;   // transposed
    } else if (tid < 192) {
        const int g = tid - 128;
        const int cell = (g < 32) ? msrc[g] : mtgt[g - 32];
        if ((cell >> 6) == blk) {
            const int c = cell & 63;
            for (int o = 0; o < 128; ++o)
                ws[OFF_MI4 + (o >> 2) * 256 + g * 4 + (o & 3)] = out_sm[c * 130 + o];
            ws[OFF_TEN + g] = t_sm[c];
        }
    }
}

// ---------------------------------------------------------------------------
// Tail1: gi/gh for all 768 gate-rows x 64 gathered cells.  Grid 192 x 256.
// ---------------------------------------------------------------------------
__global__ __launch_bounds__(256) void k_tail1(
    const float* __restrict__ W_ih, const float* __restrict__ W_hh,
    const float* __restrict__ b_ih, const float* __restrict__ b_hh,
    float* __restrict__ ws)
{
    const int lane = threadIdx.x & 63;
    const int w    = threadIdx.x >> 6;
    const int row  = __builtin_amdgcn_readfirstlane(blockIdx.x * 4 + w);
    const float* mi4 = ws + OFF_MI4;
    const float* hh4 = ws + OFF_HH4;

    const float* wi = W_ih + row * 129;
    float gi = b_ih[row];
#pragma unroll 8
    for (int q = 0; q < 32; ++q) {
        float4 a = *(const float4*)(mi4 + q * 256 + lane * 4);
        gi = fmaf(wi[4 * q + 0], a.x, gi);
        gi = fmaf(wi[4 * q + 1], a.y, gi);
        gi = fmaf(wi[4 * q + 2], a.z, gi);
        gi = fmaf(wi[4 * q + 3], a.w, gi);
    }
    gi = fmaf(ws[OFF_TEN + lane], wi[128], gi);

    const float* wh = W_hh + (size_t)row * 256;
    float gh = b_hh[row];
#pragma unroll 8
    for (int q = 0; q < 64; ++q) {
        float4 a = *(const float4*)(hh4 + q * 256 + lane * 4);
        float4 b = *(const float4*)(wh + 4 * q);
        gh = fmaf(b.x, a.x, gh);
        gh = fmaf(b.y, a.y, gh);
        gh = fmaf(b.z, a.z, gh);
        gh = fmaf(b.w, a.w, gh);
    }
    ws[OFF_GI + row * 64 + lane] = gi;
    ws[OFF_GH + row * 64 + lane] = gh;
}

// ---------------------------------------------------------------------------
// Tail2: GRU elementwise + nat + morphism partials.  Grid 32 x 512.
// ---------------------------------------------------------------------------
__global__ __launch_bounds__(512) void k_tail2(
    const float* __restrict__ nat_w, const float* __restrict__ morph_w,
    const int* __restrict__ step, float* __restrict__ ws)
{
    __shared__ float hd[2][256];
    __shared__ float hn[2][256];
    const int tid = threadIdx.x, half = tid >> 8, t = tid & 255, m = blockIdx.x;
    const int g = half * 32 + m;

    const float i_r = ws[OFF_GI + (0 * 256 + t) * 64 + g];
    const float i_z = ws[OFF_GI + (1 * 256 + t) * 64 + g];
    const float i_n = ws[OFF_GI + (2 * 256 + t) * 64 + g];
    const float h_r = ws[OFF_GH + (0 * 256 + t) * 64 + g];
    const float h_z = ws[OFF_GH + (1 * 256 + t) * 64 + g];
    const float h_n = ws[OFF_GH + (2 * 256 + t) * 64 + g];
    const float hv  = ws[OFF_HH4 + (t >> 2) * 256 + g * 4 + (t & 3)];

    const float r  = 1.f / (1.f + expf(-(i_r + h_r)));
    const float z  = 1.f / (1.f + expf(-(i_z + h_z)));
    const float nn = tanhf(i_n + r * h_n);
    const float hid = (1.f - z) * nn + z * hv;

    hd[half][t] = hid;
    __syncthreads();
    if (step[0] % 3 == 0) {
        const float4* wr = (const float4*)(nat_w + (size_t)t * 256);
        float s = 0.f;
        for (int q = 0; q < 64; ++q) {
            float4 wq = wr[q];
            s = fmaf(wq.x, hd[half][4 * q + 0], s);
            s = fmaf(wq.y, hd[half][4 * q + 1], s);
            s = fmaf(wq.z, hd[half][4 * q + 2], s);
            s = fmaf(wq.w, hd[half][4 * q + 3], s);
        }
        hn[half][t] = s;
    } else {
        hn[half][t] = hid;
    }
    __syncthreads();

    const float* wm = morph_w + (size_t)m * 65536;
    if (half == 0) {
        const float4* r_ = (const float4*)(wm + (size_t)t * 256);
        float L = 0.f;
        for (int q = 0; q < 64; ++q) {
            float4 wq = r_[q];
            L = fmaf(wq.x, hn[0][4 * q + 0], L);
            L = fmaf(wq.y, hn[0][4 * q + 1], L);
            L = fmaf(wq.z, hn[0][4 * q + 2], L);
            L = fmaf(wq.w, hn[0][4 * q + 3], L);
        }
        ws[OFF_PLIM + m * 256 + t] = L;
    } else {
        float C = 0.f;
        for (int j = 0; j < 256; ++j)
            C = fmaf(wm[j * 256 + t], hn[1][j], C);
        ws[OFF_PCOL + m * 256 + t] = C;
    }
}

// ---------------------------------------------------------------------------
// Out: blocks 0..127 -> combined_out[o]; block 128 -> avg_tension. 129 x 256.
// ---------------------------------------------------------------------------
__global__ __launch_bounds__(256) void k_out(const float* __restrict__ ws,
                                             float* __restrict__ out)
{
    __shared__ float red[256];
    const int b = blockIdx.x, t = threadIdx.x;
    if (b < 128) {
        float so = 0.f, se = 0.f;
        for (int i = t; i < 1024; i += 256) {
            so += ws[OFF_POUT + b * 1024 + i];   // transposed: contiguous
            se += ws[OFF_PE + i];
        }
        red[t] = so; __syncthreads();
        for (int s = 128; s > 0; s >>= 1) { if (t < s) red[t] += red[t + s]; __syncthreads(); }
        const float SO = red[0]; __syncthreads();
        red[t] = se; __syncthreads();
        for (int s = 128; s > 0; s >>= 1) { if (t < s) red[t] += red[t + s]; __syncthreads(); }
        if (t == 0) out[b] = SO / red[0];
    } else {
        float pt = 0.f;
        for (int i = t; i < 1024; i += 256) pt += ws[OFF_PT + i];
        float L = 0.f, C = 0.f;
        for (int m = 0; m < 32; ++m) {
            L += ws[OFF_PLIM + m * 256 + t];
            C += ws[OFF_PCOL + m * 256 + t];
        }
        const float d = (L - C) * (1.f / 32.f);
        red[t] = d * d; __syncthreads();
        for (int s = 128; s > 0; s >>= 1) { if (t < s) red[t] += red[t + s]; __syncthreads(); }
        const float cat = red[0] * (1.f / 256.f); __syncthreads();
        red[t] = pt; __syncthreads();
        for (int s = 128; s > 0; s >>= 1) { if (t < s) red[t] += red[t + s]; __syncthreads(); }
        if (t == 0) out[128] = red[0] * (1.f / 65536.f) + 0.1f * cat;
    }
}

// ---------------------------------------------------------------------------
extern "C" void kernel_launch(void* const* d_in, const int* in_sizes, int n_in,
                              void* d_out, int out_size, void* d_ws, size_t ws_size,
                              hipStream_t stream)
{
    const float* x     = (const float*)d_in[0];
    const float* hidd  = (const float*)d_in[1];
    const float* Wa1   = (const float*)d_in[2];
    const float* ba1   = (const float*)d_in[3];
    const float* Wa2   = (const float*)d_in[4];
    const float* ba2   = (const float*)d_in[5];
    const float* Wg1   = (const float*)d_in[6];
    const float* bg1   = (const float*)d_in[7];
    const float* Wg2   = (const float*)d_in[8];
    const float* bg2   = (const float*)d_in[9];
    const float* W_ih  = (const float*)d_in[10];
    const float* W_hh  = (const float*)d_in[11];
    const float* b_ih  = (const float*)d_in[12];
    const float* b_hh  = (const float*)d_in[13];
    const float* nat_w = (const float*)d_in[14];
    const float* mw    = (const float*)d_in[15];
    const int*   msrc  = (const int*)d_in[16];
    const int*   mtgt  = (const int*)d_in[17];
    const int*   step  = (const int*)d_in[18];

    float* out = (float*)d_out;
    float* ws  = (float*)d_ws;

    k_prep <<<321, 256, 0, stream>>>(x, hidd, Wa1, ba1, Wa2, ba2, Wg1, bg1, Wg2, bg2, msrc, mtgt, ws);
    k_g1   <<<256, 1024, 0, stream>>>(hidd, ws);
    k_g2   <<<1024, 512, 0, stream>>>(msrc, mtgt, ws);
    k_tail1<<<192, 256, 0, stream>>>(W_ih, W_hh, b_ih, b_hh, ws);
    k_tail2<<<32, 512, 0, stream>>>(nat_w, mw, step, ws);
    k_out  <<<129, 256, 0, stream>>>(ws, out);
}

// Round 5
// 82.398 us; speedup vs baseline: 1.7218x; 1.7218x over previous
//
#include <hip/hip_runtime.h>
#include <math.h>

#define N_CELLS 65536

// ---- workspace layout (float offsets) ----
#define OFF_W1B   0          // bf16 [32 sk][256 n][8 j]
#define OFF_W2A   32768      // bf16 [32 sk][128 o][8 j]
#define OFF_XW1B  49152      // f32 [256]
#define OFF_B2D   49408      // f32 [128]
#define OFF_PT    49536      // f32 [1024]
#define OFF_PE    50560      // f32 [1024]
#define OFF_POUT  51584      // f32 [1024 blk][128 o]
#define OFF_MI4   182656     // f32 [32 q][64 g][4]
#define OFF_TEN   190848     // f32 [64]
#define OFF_HH4   190912     // f32 [64 j4][64 g][4]
#define OFF_GI    207296     // f32 [768][64]
#define OFF_GH    256448     // f32 [768][64]
#define OFF_PLIM  305600     // f32 [32][256]
#define OFF_PCOL  313792     // f32 [32][256]  (ends 321984)
#define OFF_GMSK  322048     // u64 [1024]

typedef short bf16x8 __attribute__((ext_vector_type(8)));
typedef short s16x4  __attribute__((ext_vector_type(4)));
typedef float f32x4  __attribute__((ext_vector_type(4)));

__device__ __forceinline__ unsigned short f2bf(float f) {
    unsigned u = __builtin_bit_cast(unsigned, f);
    u += 0x7FFFu + ((u >> 16) & 1u);          // RNE
    return (unsigned short)(u >> 16);
}

__device__ __forceinline__ bf16x8 cvt8(float4 a, float4 b) {
    bf16x8 v;
    v[0] = (short)f2bf(a.x); v[1] = (short)f2bf(a.y);
    v[2] = (short)f2bf(a.z); v[3] = (short)f2bf(a.w);
    v[4] = (short)f2bf(b.x); v[5] = (short)f2bf(b.y);
    v[6] = (short)f2bf(b.z); v[7] = (short)f2bf(b.w);
    return v;
}

// ---------------------------------------------------------------------------
// Prep.  Grid 322 x 256.
// b<256: pack W1/W2' bf16 fragment layout.  b==256: xw1b/b2d.
// b 257..320: HH4 gather.  b==321: gathered-cell block bitmask.
// ---------------------------------------------------------------------------
__global__ __launch_bounds__(256) void k_prep(
    const float* __restrict__ x, const float* __restrict__ hiddens,
    const float* __restrict__ Wa1, const float* __restrict__ ba1,
    const float* __restrict__ Wa2, const float* __restrict__ ba2,
    const float* __restrict__ Wg1, const float* __restrict__ bg1,
    const float* __restrict__ Wg2, const float* __restrict__ bg2,
    const int* __restrict__ msrc, const int* __restrict__ mtgt,
    float* __restrict__ ws)
{
    const int b = blockIdx.x, t = threadIdx.x;
    unsigned short* w1b = (unsigned short*)(ws + OFF_W1B);
    unsigned short* w2a = (unsigned short*)(ws + OFF_W2A);
    if (b < 256) {
        const int n = b;           // t = k index (sk = t>>3, j = t&7)
        const float* row = (n < 128) ? &Wa1[n * 384] : &Wg1[(n - 128) * 384];
        const int sk = t >> 3;
        w1b[(sk * 256 + n) * 8 + (t & 7)] = f2bf(row[128 + t]);
        if (n < 128) {   // W2'[o=n][k=t] : k<128 -> Wa2, else -Wg2
            float w2 = (t < 128) ? Wa2[n * 128 + t] : -Wg2[n * 128 + (t - 128)];
            w2a[(sk * 128 + n) * 8 + (t & 7)] = f2bf(w2);
        }
    } else if (b == 256) {
        const int n = t;
        const float* wr = (n < 128) ? &Wa1[n * 384] : &Wg1[(n - 128) * 384];
        float s = (n < 128) ? ba1[n] : bg1[n - 128];
        for (int j = 0; j < 128; ++j) s = fmaf(x[j], wr[j], s);
        ws[OFF_XW1B + n] = s;
        if (n < 128) ws[OFF_B2D + n] = ba2[n] - bg2[n];
    } else if (b < 321) {
        const int g = b - 257;     // 0..63
        const int cell = (g < 32) ? msrc[g] : mtgt[g - 32];
        ws[OFF_HH4 + (t >> 2) * 256 + g * 4 + (t & 3)] = hiddens[(size_t)cell * 256 + t];
    } else {
        unsigned long long* gm = (unsigned long long*)(ws + OFF_GMSK);
        for (int i = t; i < 1024; i += 256) gm[i] = 0ull;
        __syncthreads();
        if (t < 64) {
            const int cell = (t < 32) ? msrc[t] : mtgt[t - 32];
            atomicOr(&gm[cell >> 6], 1ull << t);
        }
    }
}

// ---------------------------------------------------------------------------
// Main fused kernel.  Grid 1024 x 512 (8 waves), 2 blocks/CU (67 KB LDS).
// GEMM1: D1[n][c] += W1frag(global,prefetch) x h(LDS,swizzled); 8 waves x 32n x 64c.
// h1 -> LDS bf16 (swizzled).  GEMM2: 8 waves x 16o x 64c.  Register epilogue.
// ---------------------------------------------------------------------------
__global__ __launch_bounds__(512, 4) void k_main(
    const float* __restrict__ hiddens,
    const int* __restrict__ msrc, const int* __restrict__ mtgt,
    float* __restrict__ ws)
{
    __shared__ __align__(16) short hB[64 * 256];    // 32 KB bf16 h tile (chunk^=(c&7))
    __shared__ __align__(16) short h1B[64 * 256];   // 32 KB bf16 h1 tile (same swizzle)
    __shared__ float part[512];
    __shared__ float e_sm[64], t_sm[64];
    __shared__ int gid_sm[64];

    const int tid = threadIdx.x;
    const int lane = tid & 63, wid = tid >> 6;
    const int l15 = lane & 15, l4 = lane >> 4;
    const int blk = blockIdx.x;
    const int cell0 = blk * 64;

    if (tid < 64) gid_sm[tid] = (tid < 32) ? msrc[tid] : mtgt[tid - 32];

    const uint4* w1g = (const uint4*)(ws + OFF_W1B);
    const uint4* w2g = (const uint4*)(ws + OFF_W2A);

    // prefetch GEMM1 step-0 A-frags (L2-resident packed weights)
    uint4 aw0 = w1g[l4 * 256 + wid * 32 + l15];
    uint4 aw1 = w1g[l4 * 256 + wid * 32 + 16 + l15];

    // ---- stage h tile: thread owns row c = tid>>3, 128 B contiguous ----
    {
        const int c = tid >> 3;
        const float* src = hiddens + (size_t)(cell0 + c) * 256 + (tid & 7) * 32;
        float4 va[4], vb[4];
#pragma unroll
        for (int it = 0; it < 4; ++it) {
            va[it] = *(const float4*)(src + it * 8);
            vb[it] = *(const float4*)(src + it * 8 + 4);
        }
#pragma unroll
        for (int it = 0; it < 4; ++it) {
            const int chunk = (tid & 7) * 4 + it;
            *(bf16x8*)&hB[c * 256 + ((chunk ^ (c & 7)) << 3)] = cvt8(va[it], vb[it]);
        }
    }
    __syncthreads();

    // ---- GEMM1 ----
    f32x4 acc[2][4];
#pragma unroll
    for (int nt = 0; nt < 2; ++nt)
#pragma unroll
        for (int ct = 0; ct < 4; ++ct) acc[nt][ct] = (f32x4)0.f;

#pragma unroll
    for (int s = 0; s < 8; ++s) {
        uint4 an0, an1;
        if (s < 7) {
            an0 = w1g[((s + 1) * 4 + l4) * 256 + wid * 32 + l15];
            an1 = w1g[((s + 1) * 4 + l4) * 256 + wid * 32 + 16 + l15];
        } else {
            an0 = w2g[l4 * 128 + wid * 16 + l15];   // GEMM2 step-0 prefetch
            an1 = an0;
        }
        bf16x8 bfr[4];
#pragma unroll
        for (int ct = 0; ct < 4; ++ct) {
            const int c = ct * 16 + l15;
            bfr[ct] = *(const bf16x8*)&hB[c * 256 + (((s * 4 + l4) ^ (l15 & 7)) << 3)];
        }
        const bf16x8 af0 = __builtin_bit_cast(bf16x8, aw0);
        const bf16x8 af1 = __builtin_bit_cast(bf16x8, aw1);
#pragma unroll
        for (int ct = 0; ct < 4; ++ct) {
            acc[0][ct] = __builtin_amdgcn_mfma_f32_16x16x32_bf16(af0, bfr[ct], acc[0][ct], 0, 0, 0);
            acc[1][ct] = __builtin_amdgcn_mfma_f32_16x16x32_bf16(af1, bfr[ct], acc[1][ct], 0, 0, 0);
        }
        aw0 = an0; aw1 = an1;
    }

    // ---- bias + relu -> h1B (bf16, swizzled) ----
    {
        float4 xb[2];
        xb[0] = *(const float4*)(ws + OFF_XW1B + wid * 32 + l4 * 4);
        xb[1] = *(const float4*)(ws + OFF_XW1B + wid * 32 + 16 + l4 * 4);
#pragma unroll
        for (int nt = 0; nt < 2; ++nt) {
            const int n0 = wid * 32 + nt * 16 + l4 * 4;
            const int chunk = n0 >> 3;              // wid*4 + nt*2 + (l4>>1)
            const float bx[4] = {xb[nt].x, xb[nt].y, xb[nt].z, xb[nt].w};
#pragma unroll
            for (int ct = 0; ct < 4; ++ct) {
                const int c = ct * 16 + l15;
                s16x4 pk;
#pragma unroll
                for (int r = 0; r < 4; ++r)
                    pk[r] = (short)f2bf(fmaxf(acc[nt][ct][r] + bx[r], 0.f));
                *(s16x4*)&h1B[c * 256 + ((chunk ^ (l15 & 7)) << 3) + (l4 & 1) * 4] = pk;
            }
        }
    }
    __syncthreads();

    // ---- GEMM2 ----
    f32x4 acc2[4];
#pragma unroll
    for (int ct = 0; ct < 4; ++ct) acc2[ct] = (f32x4)0.f;

    uint4 a2 = aw0;   // prefetched
#pragma unroll
    for (int s = 0; s < 8; ++s) {
        uint4 a2n;
        if (s < 7) a2n = w2g[((s + 1) * 4 + l4) * 128 + wid * 16 + l15];
        bf16x8 b2[4];
#pragma unroll
        for (int ct = 0; ct < 4; ++ct) {
            const int c = ct * 16 + l15;
            b2[ct] = *(const bf16x8*)&h1B[c * 256 + (((s * 4 + l4) ^ (l15 & 7)) << 3)];
        }
        const bf16x8 af = __builtin_bit_cast(bf16x8, a2);
#pragma unroll
        for (int ct = 0; ct < 4; ++ct)
            acc2[ct] = __builtin_amdgcn_mfma_f32_16x16x32_bf16(af, b2[ct], acc2[ct], 0, 0, 0);
        a2 = a2n;
    }

    // ---- register epilogue ----
    float outv[4][4];
    {
        float4 bd = *(const float4*)(ws + OFF_B2D + wid * 16 + l4 * 4);
        const float bv[4] = {bd.x, bd.y, bd.z, bd.w};
#pragma unroll
        for (int ct = 0; ct < 4; ++ct)
#pragma unroll
            for (int r = 0; r < 4; ++r)
                outv[ct][r] = acc2[ct][r] + bv[r];
    }

    // tension partials: per-wave sum over its 16 o's
#pragma unroll
    for (int ct = 0; ct < 4; ++ct) {
        float sq = 0.f;
#pragma unroll
        for (int r = 0; r < 4; ++r) sq = fmaf(outv[ct][r], outv[ct][r], sq);
        sq += __shfl_xor(sq, 16);
        sq += __shfl_xor(sq, 32);
        if (l4 == 0) part[wid * 64 + ct * 16 + l15] = sq;
    }
    __syncthreads();

    const unsigned long long* gm = (const unsigned long long*)(ws + OFF_GMSK);
    if (tid < 64) {
        float s = 0.f;
#pragma unroll
        for (int w = 0; w < 8; ++w) s += part[w * 64 + tid];
        const float tv = s * (1.f / 128.f);
        const float ev = expf(tv);
        t_sm[tid] = tv; e_sm[tid] = ev;
        float pt = tv, pe = ev;
        for (int off = 32; off > 0; off >>= 1) {
            pt += __shfl_down(pt, off);
            pe += __shfl_down(pe, off);
        }
        if (tid == 0) { ws[OFF_PT + blk] = pt; ws[OFF_PE + blk] = pe; }
        unsigned long long m = gm[blk];
        while (m) {
            const int g = __builtin_ctzll(m); m &= m - 1;
            const int cg = gid_sm[g];
            if ((cg >> 6) == blk && (cg & 63) == tid) ws[OFF_TEN + g] = tv;
        }
    }
    __syncthreads();

    // weighted-out partial: wave owns 16 o's across all 64 cells
    {
        float p[4];
#pragma unroll
        for (int r = 0; r < 4; ++r) {
            float s = 0.f;
#pragma unroll
            for (int ct = 0; ct < 4; ++ct)
                s = fmaf(e_sm[ct * 16 + l15], outv[ct][r], s);
            p[r] = s;
        }
#pragma unroll
        for (int r = 0; r < 4; ++r) {
            p[r] += __shfl_xor(p[r], 1);
            p[r] += __shfl_xor(p[r], 2);
            p[r] += __shfl_xor(p[r], 4);
            p[r] += __shfl_xor(p[r], 8);
        }
        if (l15 == 0)
            *(float4*)(ws + OFF_POUT + blk * 128 + wid * 16 + l4 * 4) =
                make_float4(p[0], p[1], p[2], p[3]);
    }

    // gathered mem_in rows: scatter from registers
    {
        unsigned long long m = gm[blk];
        while (m) {
            const int g = __builtin_ctzll(m); m &= m - 1;
            const int cg = gid_sm[g];
            if ((cg >> 6) != blk) continue;
            const int c = cg & 63;
            if ((c & 15) == l15) {
                const int ct = c >> 4;
                *(float4*)(ws + OFF_MI4 + (wid * 4 + l4) * 256 + g * 4) =
                    make_float4(outv[ct][0], outv[ct][1], outv[ct][2], outv[ct][3]);
            }
        }
    }
}

// ---------------------------------------------------------------------------
// Tail1: gi/gh for 768 gate-rows x 64 gathered cells.  Grid 192 x 256.
// ---------------------------------------------------------------------------
__global__ __launch_bounds__(256) void k_tail1(
    const float* __restrict__ W_ih, const float* __restrict__ W_hh,
    const float* __restrict__ b_ih, const float* __restrict__ b_hh,
    float* __restrict__ ws)
{
    const int lane = threadIdx.x & 63;
    const int w    = threadIdx.x >> 6;
    const int row  = __builtin_amdgcn_readfirstlane(blockIdx.x * 4 + w);
    const float* mi4 = ws + OFF_MI4;
    const float* hh4 = ws + OFF_HH4;

    const float* wi = W_ih + row * 129;
    float gi = b_ih[row];
#pragma unroll 8
    for (int q = 0; q < 32; ++q) {
        float4 a = *(const float4*)(mi4 + q * 256 + lane * 4);
        gi = fmaf(wi[4 * q + 0], a.x, gi);
        gi = fmaf(wi[4 * q + 1], a.y, gi);
        gi = fmaf(wi[4 * q + 2], a.z, gi);
        gi = fmaf(wi[4 * q + 3], a.w, gi);
    }
    gi = fmaf(ws[OFF_TEN + lane], wi[128], gi);

    const float* wh = W_hh + (size_t)row * 256;
    float gh = b_hh[row];
#pragma unroll 8
    for (int q = 0; q < 64; ++q) {
        float4 a = *(const float4*)(hh4 + q * 256 + lane * 4);
        float4 b = *(const float4*)(wh + 4 * q);
        gh = fmaf(b.x, a.x, gh);
        gh = fmaf(b.y, a.y, gh);
        gh = fmaf(b.z, a.z, gh);
        gh = fmaf(b.w, a.w, gh);
    }
    ws[OFF_GI + row * 64 + lane] = gi;
    ws[OFF_GH + row * 64 + lane] = gh;
}

// ---------------------------------------------------------------------------
// Tail2: GRU elementwise + nat + morphism partials.  Grid 32 x 512.
// ---------------------------------------------------------------------------
__global__ __launch_bounds__(512) void k_tail2(
    const float* __restrict__ nat_w, const float* __restrict__ morph_w,
    const int* __restrict__ step, float* __restrict__ ws)
{
    __shared__ float hd[2][256];
    __shared__ float hn[2][256];
    const int tid = threadIdx.x, half = tid >> 8, t = tid & 255, m = blockIdx.x;
    const int g = half * 32 + m;

    const float i_r = ws[OFF_GI + (0 * 256 + t) * 64 + g];
    const float i_z = ws[OFF_GI + (1 * 256 + t) * 64 + g];
    const float i_n = ws[OFF_GI + (2 * 256 + t) * 64 + g];
    const float h_r = ws[OFF_GH + (0 * 256 + t) * 64 + g];
    const float h_z = ws[OFF_GH + (1 * 256 + t) * 64 + g];
    const float h_n = ws[OFF_GH + (2 * 256 + t) * 64 + g];
    const float hv  = ws[OFF_HH4 + (t >> 2) * 256 + g * 4 + (t & 3)];

    const float r  = 1.f / (1.f + expf(-(i_r + h_r)));
    const float z  = 1.f / (1.f + expf(-(i_z + h_z)));
    const float nn = tanhf(i_n + r * h_n);
    const float hid = (1.f - z) * nn + z * hv;

    hd[half][t] = hid;
    __syncthreads();
    if (step[0] % 3 == 0) {
        const float4* wr = (const float4*)(nat_w + (size_t)t * 256);
        float s = 0.f;
        for (int q = 0; q < 64; ++q) {
            float4 wq = wr[q];
            s = fmaf(wq.x, hd[half][4 * q + 0], s);
            s = fmaf(wq.y, hd[half][4 * q + 1], s);
            s = fmaf(wq.z, hd[half][4 * q + 2], s);
            s = fmaf(wq.w, hd[half][4 * q + 3], s);
        }
        hn[half][t] = s;
    } else {
        hn[half][t] = hid;
    }
    __syncthreads();

    const float* wm = morph_w + (size_t)m * 65536;
    if (half == 0) {
        const float4* r_ = (const float4*)(wm + (size_t)t * 256);
        float L = 0.f;
        for (int q = 0; q < 64; ++q) {
            float4 wq = r_[q];
            L = fmaf(wq.x, hn[0][4 * q + 0], L);
            L = fmaf(wq.y, hn[0][4 * q + 1], L);
            L = fmaf(wq.z, hn[0][4 * q + 2], L);
            L = fmaf(wq.w, hn[0][4 * q + 3], L);
        }
        ws[OFF_PLIM + m * 256 + t] = L;
    } else {
        float C = 0.f;
        for (int j = 0; j < 256; ++j)
            C = fmaf(wm[j * 256 + t], hn[1][j], C);
        ws[OFF_PCOL + m * 256 + t] = C;
    }
}

// ---------------------------------------------------------------------------
// Out: blocks 0..127 -> combined_out[o]; block 128 -> avg_tension. 129 x 256.
// ---------------------------------------------------------------------------
__global__ __launch_bounds__(256) void k_out(const float* __restrict__ ws,
                                             float* __restrict__ out)
{
    __shared__ float red[256];
    const int b = blockIdx.x, t = threadIdx.x;
    if (b < 128) {
        float so = 0.f, se = 0.f;
        for (int i = t; i < 1024; i += 256) {
            so += ws[OFF_POUT + i * 128 + b];
            se += ws[OFF_PE + i];
        }
        red[t] = so; __syncthreads();
        for (int s = 128; s > 0; s >>= 1) { if (t < s) red[t] += red[t + s]; __syncthreads(); }
        const float SO = red[0]; __syncthreads();
        red[t] = se; __syncthreads();
        for (int s = 128; s > 0; s >>= 1) { if (t < s) red[t] += red[t + s]; __syncthreads(); }
        if (t == 0) out[b] = SO / red[0];
    } else {
        float pt = 0.f;
        for (int i = t; i < 1024; i += 256) pt += ws[OFF_PT + i];
        float L = 0.f, C = 0.f;
        for (int m = 0; m < 32; ++m) {
            L += ws[OFF_PLIM + m * 256 + t];
            C += ws[OFF_PCOL + m * 256 + t];
        }
        const float d = (L - C) * (1.f / 32.f);
        red[t] = d * d; __syncthreads();
        for (int s = 128; s > 0; s >>= 1) { if (t < s) red[t] += red[t + s]; __syncthreads(); }
        const float cat = red[0] * (1.f / 256.f); __syncthreads();
        red[t] = pt; __syncthreads();
        for (int s = 128; s > 0; s >>= 1) { if (t < s) red[t] += red[t + s]; __syncthreads(); }
        if (t == 0) out[128] = red[0] * (1.f / 65536.f) + 0.1f * cat;
    }
}

// ---------------------------------------------------------------------------
extern "C" void kernel_launch(void* const* d_in, const int* in_sizes, int n_in,
                              void* d_out, int out_size, void* d_ws, size_t ws_size,
                              hipStream_t stream)
{
    const float* x     = (const float*)d_in[0];
    const float* hidd  = (const float*)d_in[1];
    const float* Wa1   = (const float*)d_in[2];
    const float* ba1   = (const float*)d_in[3];
    const float* Wa2   = (const float*)d_in[4];
    const float* ba2   = (const float*)d_in[5];
    const float* Wg1   = (const float*)d_in[6];
    const float* bg1   = (const float*)d_in[7];
    const float* Wg2   = (const float*)d_in[8];
    const float* bg2   = (const float*)d_in[9];
    const float* W_ih  = (const float*)d_in[10];
    const float* W_hh  = (const float*)d_in[11];
    const float* b_ih  = (const float*)d_in[12];
    const float* b_hh  = (const float*)d_in[13];
    const float* nat_w = (const float*)d_in[14];
    const float* mw    = (const float*)d_in[15];
    const int*   msrc  = (const int*)d_in[16];
    const int*   mtgt  = (const int*)d_in[17];
    const int*   step  = (const int*)d_in[18];

    float* out = (float*)d_out;
    float* ws  = (float*)d_ws;

    k_prep <<<322, 256, 0, stream>>>(x, hidd, Wa1, ba1, Wa2, ba2, Wg1, bg1, Wg2, bg2, msrc, mtgt, ws);
    k_main <<<1024, 512, 0, stream>>>(hidd, msrc, mtgt, ws);
    k_tail1<<<192, 256, 0, stream>>>(W_ih, W_hh, b_ih, b_hh, ws);
    k_tail2<<<32, 512, 0, stream>>>(nat_w, mw, step, ws);
    k_out  <<<129, 256, 0, stream>>>(ws, out);
}